// Round 1
// baseline (145.671 us; speedup 1.0000x reference)
//
#include <hip/hip_runtime.h>
#include <hip/hip_bf16.h>
#include <cstdint>

// LinearAttention on MI355X — see pipeline description in previous block.
// Requires ws_size >= ~66.3 MB.

typedef unsigned short u16;
typedef unsigned int   u32;
typedef short bf16x8 __attribute__((ext_vector_type(8)));
typedef float f32x4  __attribute__((ext_vector_type(4)));

#define HW    16384
#define CDIM  512
#define SQRTD 22.627416997969522f

__device__ __forceinline__ float bflo2f(u32 u) { union {u32 u_; float f;} c; c.u_ = u << 16;        return c.f; }
__device__ __forceinline__ float bfhi2f(u32 u) { union {u32 u_; float f;} c; c.u_ = u & 0xffff0000u; return c.f; }
__device__ __forceinline__ u16 f2bf(float f) {
  u32 x = __builtin_bit_cast(u32, f);
  u32 r = x + 0x7fffu + ((x >> 16) & 1u);
  return (u16)(r >> 16);
}

__device__ __forceinline__ void gload16(const void* g, void* l) {
  __builtin_amdgcn_global_load_lds(
      (const __attribute__((address_space(1))) void*)(uintptr_t)g,
      (__attribute__((address_space(3))) void*)(u32)(uintptr_t)l,
      16, 0, 0);
}

__global__ __launch_bounds__(256) void k_sumsq(const float* __restrict__ x, float* __restrict__ ss) {
  int t = threadIdx.x;
  int p = blockIdx.x * 512 + t * 2;
  int c0 = blockIdx.y * 64;
  const float* xp = x + (size_t)c0 * HW + p;
  float a0 = 0.f, a1 = 0.f;
  for (int c = 0; c < 64; c++) {
    float2 v = *(const float2*)(xp + (size_t)c * HW);
    a0 += v.x * v.x; a1 += v.y * v.y;
  }
  atomicAdd(&ss[p], a0);
  atomicAdd(&ss[p + 1], a1);
}

__global__ __launch_bounds__(256) void k_f2bf(const float* __restrict__ src, u16* __restrict__ dst, int n) {
  int idx = (blockIdx.x * 256 + threadIdx.x) * 4;
  if (idx >= n) return;
  float4 v = *(const float4*)(src + idx);
  ushort4 o; o.x = f2bf(v.x); o.y = f2bf(v.y); o.z = f2bf(v.z); o.w = f2bf(v.w);
  *(ushort4*)(dst + idx) = o;
}

__global__ __launch_bounds__(256) void k_xnt(const float* __restrict__ x, const float* __restrict__ ss,
                                             const float* __restrict__ g1, u16* __restrict__ xnt) {
  __shared__ float tl[64][65];
  int t = threadIdx.x;
  int p0 = blockIdx.x * 64, c0 = blockIdx.y * 64;
  #pragma unroll
  for (int i = 0; i < 4; i++) {
    int idx = i * 256 + t; int c = idx >> 4, p4 = (idx & 15) * 4;
    float4 v = *(const float4*)(x + (size_t)(c0 + c) * HW + p0 + p4);
    tl[c][p4] = v.x; tl[c][p4 + 1] = v.y; tl[c][p4 + 2] = v.z; tl[c][p4 + 3] = v.w;
  }
  __syncthreads();
  #pragma unroll
  for (int i = 0; i < 16; i++) {
    int idx = i * 256 + t; int p = idx >> 6, c = idx & 63;
    float sp = SQRTD * rsqrtf(ss[p0 + p]);
    float val = tl[c][p] * sp * (1.0f + g1[c0 + c]);
    xnt[(size_t)(p0 + p) * CDIM + c0 + c] = f2bf(val);
  }
}

template<int EPI>
__global__ __launch_bounds__(256) void k_gemm(const u16* __restrict__ A, const u16* __restrict__ Bt,
                                              int M, int N, int K,
                                              u16* __restrict__ Cb,
                                              float* __restrict__ Cf, const float* __restrict__ bias,
                                              float* __restrict__ nsq) {
  __shared__ u16 As[128 * 64], Bs[128 * 64];
  __shared__ float css[128];
  int t = threadIdx.x;
  int lane = t & 63, w = t >> 6;
  int lq = lane >> 4, lr = lane & 15;
  int bn = blockIdx.x, bm = blockIdx.y;
  if (EPI == 1 && t < 128) css[t] = 0.f;
  int wm = (w >> 1) * 64, wn = (w & 1) * 64;
  f32x4 acc[4][4] = {};
  const u16* Abase = A + (size_t)bm * 128 * K;
  const u16* Bbase = Bt + (size_t)bn * 128 * K;
  int nk = K >> 6;
  for (int kt = 0; kt < nk; kt++) {
    #pragma unroll
    for (int i = 0; i < 4; i++) {
      int s = i * 256 + t;
      int row = s >> 3, slot = (s & 7) ^ (row & 7);
      gload16(Abase + (size_t)row * K + kt * 64 + slot * 8, &As[(i * 256 + (w << 6)) * 8]);
    }
    #pragma unroll
    for (int i = 0; i < 4; i++) {
      int s = i * 256 + t;
      int row = s >> 3, slot = (s & 7) ^ (row & 7);
      gload16(Bbase + (size_t)row * K + kt * 64 + slot * 8, &Bs[(i * 256 + (w << 6)) * 8]);
    }
    __syncthreads();
    #pragma unroll
    for (int kk = 0; kk < 2; kk++) {
      bf16x8 af[4], bv[4];
      #pragma unroll
      for (int mi = 0; mi < 4; mi++) {
        int row = wm + mi * 16 + lr;
        int slot = ((kk << 2) + lq) ^ (row & 7);
        af[mi] = *(const bf16x8*)&As[row * 64 + slot * 8];
      }
      #pragma unroll
      for (int nj = 0; nj < 4; nj++) {
        int row = wn + nj * 16 + lr;
        int slot = ((kk << 2) + lq) ^ (row & 7);
        bv[nj] = *(const bf16x8*)&Bs[row * 64 + slot * 8];
      }
      #pragma unroll
      for (int mi = 0; mi < 4; mi++)
        #pragma unroll
        for (int nj = 0; nj < 4; nj++)
          acc[mi][nj] = __builtin_amdgcn_mfma_f32_16x16x32_bf16(af[mi], bv[nj], acc[mi][nj], 0, 0, 0);
    }
    __syncthreads();
  }
  int cm0 = bm * 128 + wm, cn0 = bn * 128 + wn;
  if (EPI == 0) {
    #pragma unroll
    for (int mi = 0; mi < 4; mi++)
      #pragma unroll
      for (int nj = 0; nj < 4; nj++) {
        int col = cn0 + nj * 16 + lr;
        #pragma unroll
        for (int r = 0; r < 4; r++) {
          int rowg = cm0 + mi * 16 + lq * 4 + r;
          Cb[(size_t)rowg * N + col] = f2bf(acc[mi][nj][r]);
        }
      }
  } else {
    float ps[4] = {0.f, 0.f, 0.f, 0.f};
    #pragma unroll
    for (int mi = 0; mi < 4; mi++)
      #pragma unroll
      for (int r = 0; r < 4; r++) {
        int rowg = cm0 + mi * 16 + lq * 4 + r;
        float b = bias[rowg];
        #pragma unroll
        for (int nj = 0; nj < 4; nj++) {
          int col = cn0 + nj * 16 + lr;
          float v = acc[mi][nj][r] + b;
          Cf[(size_t)rowg * N + col] = v;
          ps[nj] += v * v;
        }
      }
    #pragma unroll
    for (int nj = 0; nj < 4; nj++) atomicAdd(&css[wn + nj * 16 + lr], ps[nj]);
    __syncthreads();
    if (t < 128) atomicAdd(&nsq[bn * 128 + t], css[t]);
  }
}

__global__ __launch_bounds__(256) void k_kstats(const u16* __restrict__ qkv, const float* __restrict__ memkv,
                                                float* __restrict__ kmax, float* __restrict__ kden,
                                                float* __restrict__ ctx) {
  int hd = blockIdx.x;
  int h = hd >> 6, d = hd & 63;
  int t = threadIdx.x;
  const u16* krow = qkv + (size_t)(512 + hd) * HW;
  const float* mk = memkv + ((size_t)h * 64 + d) * 4;
  __shared__ float red[4];
  float m = -1e30f;
  for (int i = 0; i < 8; i++) {
    uint4 v = *(const uint4*)(krow + (i * 256 + t) * 8);
    m = fmaxf(m, fmaxf(fmaxf(fmaxf(bflo2f(v.x), bfhi2f(v.x)), fmaxf(bflo2f(v.y), bfhi2f(v.y))),
                       fmaxf(fmaxf(bflo2f(v.z), bfhi2f(v.z)), fmaxf(bflo2f(v.w), bfhi2f(v.w)))));
  }
  if (t < 4) m = fmaxf(m, mk[t]);
  for (int o = 32; o; o >>= 1) m = fmaxf(m, __shfl_xor(m, o));
  if ((t & 63) == 0) red[t >> 6] = m;
  __syncthreads();
  float mb = fmaxf(fmaxf(red[0], red[1]), fmaxf(red[2], red[3]));
  __syncthreads();
  float s = 0.f;
  for (int i = 0; i < 8; i++) {
    uint4 v = *(const uint4*)(krow + (i * 256 + t) * 8);
    s += __expf(bflo2f(v.x) - mb) + __expf(bfhi2f(v.x) - mb)
       + __expf(bflo2f(v.y) - mb) + __expf(bfhi2f(v.y) - mb)
       + __expf(bflo2f(v.z) - mb) + __expf(bfhi2f(v.z) - mb)
       + __expf(bflo2f(v.w) - mb) + __expf(bfhi2f(v.w) - mb);
  }
  if (t < 4) s += __expf(mk[t] - mb);
  for (int o = 32; o; o >>= 1) s += __shfl_xor(s, o);
  if ((t & 63) == 0) red[t >> 6] = s;
  __syncthreads();
  float sb = red[0] + red[1] + red[2] + red[3];
  if (t == 0) { kmax[hd] = mb; kden[hd] = sb; }
  if (t < 64) {
    float acc = 0.f;
    const float* mv = memkv + (size_t)(512 + h * 64 + t) * 4;
    #pragma unroll
    for (int j = 0; j < 4; j++) acc += __expf(mk[j] - mb) * mv[j];
    ctx[(size_t)h * 4096 + d * 64 + t] = acc;
  }
}

__global__ __launch_bounds__(256) void k_ctx(const u16* __restrict__ qkv, const float* __restrict__ kmax,
                                             float* __restrict__ ctx) {
  __shared__ u16 Ws[64 * 64], Vs[64 * 64];
  __shared__ float kml[64];
  int t = threadIdx.x; int lane = t & 63, w = t >> 6, lq = lane >> 4, lr = lane & 15;
  int h = blockIdx.y; int c0 = blockIdx.x * 1024;
  if (t < 64) kml[t] = kmax[h * 64 + t];
  const u16* kbase = qkv + (size_t)(512 + h * 64) * HW + c0;
  const u16* vbase = qkv + (size_t)(1024 + h * 64) * HW + c0;
  f32x4 acc[4] = {};
  __syncthreads();
  for (int kt = 0; kt < 16; kt++) {
    #pragma unroll
    for (int i = 0; i < 2; i++) {
      int s = i * 256 + t; int row = s >> 3, sl = s & 7;
      uint4 v = *(const uint4*)(kbase + (size_t)row * HW + kt * 64 + sl * 8);
      float km = kml[row];
      uint4 ov;
      ov.x = (u32)f2bf(__expf(bflo2f(v.x) - km)) | ((u32)f2bf(__expf(bfhi2f(v.x) - km)) << 16);
      ov.y = (u32)f2bf(__expf(bflo2f(v.y) - km)) | ((u32)f2bf(__expf(bfhi2f(v.y) - km)) << 16);
      ov.z = (u32)f2bf(__expf(bflo2f(v.z) - km)) | ((u32)f2bf(__expf(bfhi2f(v.z) - km)) << 16);
      ov.w = (u32)f2bf(__expf(bflo2f(v.w) - km)) | ((u32)f2bf(__expf(bfhi2f(v.w) - km)) << 16);
      *(uint4*)&Ws[row * 64 + ((sl ^ (row & 7)) << 3)] = ov;
    }
    #pragma unroll
    for (int i = 0; i < 2; i++) {
      int s = i * 256 + t; int row = s >> 3, sl = (s & 7) ^ (row & 7);
      gload16(vbase + (size_t)row * HW + kt * 64 + sl * 8, &Vs[(i * 256 + (w << 6)) * 8]);
    }
    __syncthreads();
    #pragma unroll
    for (int kk = 0; kk < 2; kk++) {
      int rowa = w * 16 + lr;
      int sla = ((kk << 2) + lq) ^ (rowa & 7);
      bf16x8 af = *(const bf16x8*)&Ws[rowa * 64 + sla * 8];
      #pragma unroll
      for (int nj = 0; nj < 4; nj++) {
        int rowb = nj * 16 + lr;
        int slb = ((kk << 2) + lq) ^ (rowb & 7);
        bf16x8 bv = *(const bf16x8*)&Vs[rowb * 64 + slb * 8];
        acc[nj] = __builtin_amdgcn_mfma_f32_16x16x32_bf16(af, bv, acc[nj], 0, 0, 0);
      }
    }
    __syncthreads();
  }
  #pragma unroll
  for (int nj = 0; nj < 4; nj++)
    #pragma unroll
    for (int r = 0; r < 4; r++) {
      int d = w * 16 + lq * 4 + r, e = nj * 16 + lr;
      atomicAdd(&ctx[(size_t)h * 4096 + d * 64 + e], acc[nj][r]);
    }
}

__global__ __launch_bounds__(256) void k_attout(const u16* __restrict__ qkv, const float* __restrict__ ctx,
                                                const float* __restrict__ kden, u16* __restrict__ outt) {
  __shared__ u16 ctxT[64 * 72];
  __shared__ u16 qs[256 * 72];
  int t = threadIdx.x; int lane = t & 63, w = t >> 6, lq = lane >> 4, lr = lane & 15;
  int h = blockIdx.y, p0 = blockIdx.x * 256;
  #pragma unroll
  for (int i = 0; i < 16; i++) {
    int idx = i * 256 + t; int d = idx >> 6, e = idx & 63;
    float v = ctx[(size_t)h * 4096 + idx] * (0.125f / kden[h * 64 + d]);
    ctxT[e * 72 + d] = f2bf(v);
  }
  const u16* qbase = qkv + (size_t)(h * 64) * HW + p0;
  #pragma unroll
  for (int i = 0; i < 8; i++) {
    int idx = i * 256 + t; int d = idx >> 5, sp = idx & 31;
    uint4 v = *(const uint4*)(qbase + (size_t)d * HW + sp * 8);
    int p = sp * 8;
    qs[(p + 0) * 72 + d] = (u16)(v.x & 0xffff); qs[(p + 1) * 72 + d] = (u16)(v.x >> 16);
    qs[(p + 2) * 72 + d] = (u16)(v.y & 0xffff); qs[(p + 3) * 72 + d] = (u16)(v.y >> 16);
    qs[(p + 4) * 72 + d] = (u16)(v.z & 0xffff); qs[(p + 5) * 72 + d] = (u16)(v.z >> 16);
    qs[(p + 6) * 72 + d] = (u16)(v.w & 0xffff); qs[(p + 7) * 72 + d] = (u16)(v.w >> 16);
  }
  __syncthreads();
  {
    float qv[64];
    #pragma unroll
    for (int i = 0; i < 8; i++) {
      uint4 v = *(const uint4*)&qs[t * 72 + i * 8];
      qv[i * 8 + 0] = bflo2f(v.x); qv[i * 8 + 1] = bfhi2f(v.x);
      qv[i * 8 + 2] = bflo2f(v.y); qv[i * 8 + 3] = bfhi2f(v.y);
      qv[i * 8 + 4] = bflo2f(v.z); qv[i * 8 + 5] = bfhi2f(v.z);
      qv[i * 8 + 6] = bflo2f(v.w); qv[i * 8 + 7] = bfhi2f(v.w);
    }
    float m = qv[0];
    #pragma unroll
    for (int i = 1; i < 64; i++) m = fmaxf(m, qv[i]);
    float s = 0.f;
    #pragma unroll
    for (int i = 0; i < 64; i++) { qv[i] = __expf(qv[i] - m); s += qv[i]; }
    float inv = 1.0f / s;
    #pragma unroll
    for (int i = 0; i < 8; i++) {
      uint4 pk;
      pk.x = (u32)f2bf(qv[i * 8 + 0] * inv) | ((u32)f2bf(qv[i * 8 + 1] * inv) << 16);
      pk.y = (u32)f2bf(qv[i * 8 + 2] * inv) | ((u32)f2bf(qv[i * 8 + 3] * inv) << 16);
      pk.z = (u32)f2bf(qv[i * 8 + 4] * inv) | ((u32)f2bf(qv[i * 8 + 5] * inv) << 16);
      pk.w = (u32)f2bf(qv[i * 8 + 6] * inv) | ((u32)f2bf(qv[i * 8 + 7] * inv) << 16);
      *(uint4*)&qs[t * 72 + i * 8] = pk;
    }
  }
  __syncthreads();
  f32x4 acc[4][4] = {};
  #pragma unroll
  for (int kk = 0; kk < 2; kk++) {
    bf16x8 af[4], bq[4];
    #pragma unroll
    for (int mi = 0; mi < 4; mi++)
      af[mi] = *(const bf16x8*)&ctxT[(mi * 16 + lr) * 72 + kk * 32 + lq * 8];
    #pragma unroll
    for (int nj = 0; nj < 4; nj++)
      bq[nj] = *(const bf16x8*)&qs[(w * 64 + nj * 16 + lr) * 72 + kk * 32 + lq * 8];
    #pragma unroll
    for (int mi = 0; mi < 4; mi++)
      #pragma unroll
      for (int nj = 0; nj < 4; nj++)
        acc[mi][nj] = __builtin_amdgcn_mfma_f32_16x16x32_bf16(af[mi], bq[nj], acc[mi][nj], 0, 0, 0);
  }
  #pragma unroll
  for (int mi = 0; mi < 4; mi++)
    #pragma unroll
    for (int nj = 0; nj < 4; nj++) {
      int p = p0 + w * 64 + nj * 16 + lr;
      int e0 = mi * 16 + lq * 4;
      ushort4 o;
      o.x = f2bf(acc[mi][nj][0]); o.y = f2bf(acc[mi][nj][1]);
      o.z = f2bf(acc[mi][nj][2]); o.w = f2bf(acc[mi][nj][3]);
      *(ushort4*)&outt[(size_t)p * CDIM + h * 64 + e0] = o;
    }
}

__global__ __launch_bounds__(256) void k_finnorm(float* __restrict__ out, const float* __restrict__ nsq,
                                                 const float* __restrict__ g2) {
  int idx = blockIdx.x * 256 + threadIdx.x;
  int o = idx >> 12; int p = (idx & 4095) * 4;
  float sc = (1.0f + g2[o]) * SQRTD;
  float4 v = *(float4*)(out + (size_t)o * HW + p);
  float4 ns = *(const float4*)(nsq + p);
  v.x *= sc * rsqrtf(ns.x); v.y *= sc * rsqrtf(ns.y);
  v.z *= sc * rsqrtf(ns.z); v.w *= sc * rsqrtf(ns.w);
  *(float4*)(out + (size_t)o * HW + p) = v;
}

extern "C" void kernel_launch(void* const* d_in, const int* in_sizes, int n_in,
                              void* d_out, int out_size, void* d_ws, size_t ws_size,
                              hipStream_t stream) {
  (void)in_sizes; (void)n_in; (void)out_size; (void)ws_size;
  const float* x     = (const float*)d_in[0];
  const float* g1    = (const float*)d_in[1];
  const float* qkvw  = (const float*)d_in[2];
  const float* memkv = (const float*)d_in[3];
  const float* convw = (const float*)d_in[4];
  const float* convb = (const float*)d_in[5];
  const float* g2    = (const float*)d_in[6];
  float* out = (float*)d_out;
  char* ws = (char*)d_ws;

  float* ss   = (float*)(ws);
  float* nsq  = (float*)(ws + 65536);
  float* kmax = (float*)(ws + 131072);
  float* kden = (float*)(ws + 133120);
  float* ctx  = (float*)(ws + 135168);
  u16* wbf    = (u16*)(ws + 266240);
  u16* cbf    = (u16*)(ws + 1839104);
  u16* xnt    = (u16*)(ws + 2363392);
  u16* outt   = xnt;  // alias: xnt dead after GEMM1, outt written after
  u16* qkv    = (u16*)(ws + 19140608);

  hipMemsetAsync(ss, 0, 65536, stream);
  hipMemsetAsync(nsq, 0, 65536, stream);

  k_f2bf<<<768, 256, 0, stream>>>(qkvw, wbf, 1536 * 512);
  k_f2bf<<<256, 256, 0, stream>>>(convw, cbf, 512 * 512);
  k_sumsq<<<dim3(32, 8), 256, 0, stream>>>(x, ss);
  k_xnt<<<dim3(256, 8), 256, 0, stream>>>(x, ss, g1, xnt);
  k_gemm<0><<<dim3(128, 12), 256, 0, stream>>>(wbf, xnt, 1536, 16384, 512, qkv, nullptr, nullptr, nullptr);
  k_kstats<<<512, 256, 0, stream>>>(qkv, memkv, kmax, kden, ctx);
  k_ctx<<<dim3(16, 8), 256, 0, stream>>>(qkv, kmax, ctx);
  k_attout<<<dim3(64, 8), 256, 0, stream>>>(qkv, ctx, kden, outt);
  k_gemm<1><<<dim3(128, 4), 256, 0, stream>>>(cbf, outt, 512, 16384, 512, nullptr, out, convb, nsq);
  k_finnorm<<<8192, 256, 0, stream>>>(out, nsq, g2);
}

// Round 2
// 129.547 us; speedup vs baseline: 1.1245x; 1.1245x over previous
//
#include <hip/hip_runtime.h>
#include <hip/hip_bf16.h>
#include <cstdint>

// LinearAttention on MI355X — fused pipeline, no memsets, no max-pass.
//  k_ctxinit : den[hd]  = sum_j exp(mk);  ctx[h][d][e] = sum_j exp(mk)*mv
//  k_f2bf    : weights fp32 -> bf16
//  k_sumsq   : pss[cblk][p] partial sum of squares (plain stores)
//  k_xnt     : xn^T[p][c] bf16, rms1 scale folded
//  k_gemm1   : qkv = qkv_w @ xn ; epilogue: q-rows -> softmax_d(q),
//              k-rows -> exp(k) + row-sum atomics into den, v-rows raw
//  k_ctx     : ctx += exp(k) @ v^T  (MFMA, both operands global_load_lds)
//  k_attout  : out_t[p][c] = (ctx*0.125/den)^T @ q'
//  k_gemm2   : d_out = rms2( conv_w @ out_t + b ) fused (BM=512 in-block)

typedef unsigned short u16;
typedef unsigned int   u32;
typedef short bf16x8 __attribute__((ext_vector_type(8)));
typedef float f32x4  __attribute__((ext_vector_type(4)));

#define HW    16384
#define CDIM  512
#define SQRTD 22.627416997969522f

__device__ __forceinline__ float bflo2f(u32 u) { union {u32 u_; float f;} c; c.u_ = u << 16;        return c.f; }
__device__ __forceinline__ float bfhi2f(u32 u) { union {u32 u_; float f;} c; c.u_ = u & 0xffff0000u; return c.f; }
__device__ __forceinline__ u16 f2bf(float f) {
  u32 x = __builtin_bit_cast(u32, f);
  u32 r = x + 0x7fffu + ((x >> 16) & 1u);
  return (u16)(r >> 16);
}

__device__ __forceinline__ void gload16(const void* g, void* l) {
  __builtin_amdgcn_global_load_lds(
      (const __attribute__((address_space(1))) void*)(uintptr_t)g,
      (__attribute__((address_space(3))) void*)(u32)(uintptr_t)l,
      16, 0, 0);
}

// ---------------- den/ctx init with mem_kv contribution -----------------
__global__ __launch_bounds__(256) void k_ctxinit(const float* __restrict__ memkv,
                                                 float* __restrict__ den, float* __restrict__ ctx) {
  int h = blockIdx.x;
  int t = threadIdx.x;
  if (t < 64) {
    const float* mk = memkv + ((size_t)h * 64 + t) * 4;
    den[h * 64 + t] = __expf(mk[0]) + __expf(mk[1]) + __expf(mk[2]) + __expf(mk[3]);
  }
  #pragma unroll
  for (int i = 0; i < 16; i++) {
    int idx = i * 256 + t; int d = idx >> 6, e = idx & 63;
    const float* mk = memkv + ((size_t)h * 64 + d) * 4;
    const float* mv = memkv + (size_t)(512 + h * 64 + e) * 4;
    ctx[(size_t)h * 4096 + idx] = __expf(mk[0]) * mv[0] + __expf(mk[1]) * mv[1]
                                + __expf(mk[2]) * mv[2] + __expf(mk[3]) * mv[3];
  }
}

__global__ __launch_bounds__(256) void k_f2bf(const float* __restrict__ src, u16* __restrict__ dst, int n) {
  int idx = (blockIdx.x * 256 + threadIdx.x) * 4;
  if (idx >= n) return;
  float4 v = *(const float4*)(src + idx);
  ushort4 o; o.x = f2bf(v.x); o.y = f2bf(v.y); o.z = f2bf(v.z); o.w = f2bf(v.w);
  *(ushort4*)(dst + idx) = o;
}

// ---------------- rms1 partial sums (no atomics, no init) ---------------
__global__ __launch_bounds__(256) void k_sumsq(const float* __restrict__ x, float* __restrict__ pss) {
  int t = threadIdx.x;
  int p = blockIdx.x * 512 + t * 2;
  int c0 = blockIdx.y * 64;
  const float* xp = x + (size_t)c0 * HW + p;
  float a0 = 0.f, a1 = 0.f;
  for (int c = 0; c < 64; c++) {
    float2 v = *(const float2*)(xp + (size_t)c * HW);
    a0 += v.x * v.x; a1 += v.y * v.y;
  }
  *(float2*)&pss[(size_t)blockIdx.y * HW + p] = make_float2(a0, a1);
}

__global__ __launch_bounds__(256) void k_xnt(const float* __restrict__ x, const float* __restrict__ pss,
                                             const float* __restrict__ g1, u16* __restrict__ xnt) {
  __shared__ float tl[64][65];
  __shared__ float rs[64];
  __shared__ float gl[64];
  int t = threadIdx.x;
  int p0 = blockIdx.x * 64, c0 = blockIdx.y * 64;
  #pragma unroll
  for (int i = 0; i < 4; i++) {
    int idx = i * 256 + t; int c = idx >> 4, p4 = (idx & 15) * 4;
    float4 v = *(const float4*)(x + (size_t)(c0 + c) * HW + p0 + p4);
    tl[c][p4] = v.x; tl[c][p4 + 1] = v.y; tl[c][p4 + 2] = v.z; tl[c][p4 + 3] = v.w;
  }
  if (t < 64) {
    float s = 0.f;
    #pragma unroll
    for (int j = 0; j < 8; j++) s += pss[(size_t)j * HW + p0 + t];
    rs[t] = SQRTD * rsqrtf(s);
    gl[t] = 1.0f + g1[c0 + t];
  }
  __syncthreads();
  #pragma unroll
  for (int i = 0; i < 16; i++) {
    int idx = i * 256 + t; int p = idx >> 6, c = idx & 63;
    xnt[(size_t)(p0 + p) * CDIM + c0 + c] = f2bf(tl[c][p] * rs[p] * gl[c]);
  }
}

// ---------------- GEMM1: qkv = qkv_w @ xn, fused softmax epilogues ------
__global__ __launch_bounds__(256) void k_gemm1(const u16* __restrict__ A, const u16* __restrict__ Bt,
                                               u16* __restrict__ Cb, float* __restrict__ den) {
  const int K = CDIM, N = HW;
  __shared__ u16 As[128 * 64], Bs[128 * 64];
  int t = threadIdx.x;
  int lane = t & 63, w = t >> 6;
  int lq = lane >> 4, lr = lane & 15;
  // XCD-chunked swizzle: 1536 blocks, 192 per XCD, bm fastest within XCD
  int wg = blockIdx.x;
  int gt = (wg & 7) * 192 + (wg >> 3);
  int bn = gt / 12, bm = gt % 12;
  int wm = (w >> 1) * 64, wn = (w & 1) * 64;
  f32x4 acc[4][4] = {};
  const u16* Abase = A + (size_t)bm * 128 * K;
  const u16* Bbase = Bt + (size_t)bn * 128 * K;
  for (int kt = 0; kt < 8; kt++) {
    #pragma unroll
    for (int i = 0; i < 4; i++) {
      int s = i * 256 + t;
      int row = s >> 3, slot = (s & 7) ^ (row & 7);
      gload16(Abase + (size_t)row * K + kt * 64 + slot * 8, &As[(i * 256 + (w << 6)) * 8]);
    }
    #pragma unroll
    for (int i = 0; i < 4; i++) {
      int s = i * 256 + t;
      int row = s >> 3, slot = (s & 7) ^ (row & 7);
      gload16(Bbase + (size_t)row * K + kt * 64 + slot * 8, &Bs[(i * 256 + (w << 6)) * 8]);
    }
    __syncthreads();
    #pragma unroll
    for (int kk = 0; kk < 2; kk++) {
      bf16x8 af[4], bv[4];
      #pragma unroll
      for (int mi = 0; mi < 4; mi++) {
        int row = wm + mi * 16 + lr;
        int slot = ((kk << 2) + lq) ^ (row & 7);
        af[mi] = *(const bf16x8*)&As[row * 64 + slot * 8];
      }
      #pragma unroll
      for (int nj = 0; nj < 4; nj++) {
        int row = wn + nj * 16 + lr;
        int slot = ((kk << 2) + lq) ^ (row & 7);
        bv[nj] = *(const bf16x8*)&Bs[row * 64 + slot * 8];
      }
      #pragma unroll
      for (int mi = 0; mi < 4; mi++)
        #pragma unroll
        for (int nj = 0; nj < 4; nj++)
          acc[mi][nj] = __builtin_amdgcn_mfma_f32_16x16x32_bf16(af[mi], bv[nj], acc[mi][nj], 0, 0, 0);
    }
    __syncthreads();
  }
  int cm0 = bm * 128 + wm, cn0 = bn * 128 + wn;
  if (bm < 4) {
    // q rows: softmax over d (64 rows per wave = one head) in-register
    #pragma unroll
    for (int nj = 0; nj < 4; nj++) {
      float e[4][4];
      float s = 0.f;
      #pragma unroll
      for (int mi = 0; mi < 4; mi++)
        #pragma unroll
        for (int r = 0; r < 4; r++) { e[mi][r] = __expf(acc[mi][nj][r]); s += e[mi][r]; }
      s += __shfl_xor(s, 16);
      s += __shfl_xor(s, 32);
      float inv = 1.0f / s;
      int col = cn0 + nj * 16 + lr;
      #pragma unroll
      for (int mi = 0; mi < 4; mi++)
        #pragma unroll
        for (int r = 0; r < 4; r++) {
          int rowg = cm0 + mi * 16 + lq * 4 + r;
          Cb[(size_t)rowg * N + col] = f2bf(e[mi][r] * inv);
        }
    }
  } else if (bm < 8) {
    // k rows: store exp(k); accumulate row denominators
    #pragma unroll
    for (int mi = 0; mi < 4; mi++)
      #pragma unroll
      for (int r = 0; r < 4; r++) {
        int rowg = cm0 + mi * 16 + lq * 4 + r;
        float rsum = 0.f;
        #pragma unroll
        for (int nj = 0; nj < 4; nj++) {
          float e = __expf(acc[mi][nj][r]);
          rsum += e;
          Cb[(size_t)rowg * N + cn0 + nj * 16 + lr] = f2bf(e);
        }
        rsum += __shfl_xor(rsum, 1); rsum += __shfl_xor(rsum, 2);
        rsum += __shfl_xor(rsum, 4); rsum += __shfl_xor(rsum, 8);
        if (lr == 0) atomicAdd(&den[rowg - 512], rsum);
      }
  } else {
    // v rows: raw bf16
    #pragma unroll
    for (int mi = 0; mi < 4; mi++)
      #pragma unroll
      for (int nj = 0; nj < 4; nj++) {
        int col = cn0 + nj * 16 + lr;
        #pragma unroll
        for (int r = 0; r < 4; r++) {
          int rowg = cm0 + mi * 16 + lq * 4 + r;
          Cb[(size_t)rowg * N + col] = f2bf(acc[mi][nj][r]);
        }
      }
  }
}

// ---------------- ctx += exp(k) @ v^T -----------------------------------
__global__ __launch_bounds__(256) void k_ctx(const u16* __restrict__ qkv, float* __restrict__ ctx) {
  __shared__ u16 Ws[64 * 64], Vs[64 * 64];
  int t = threadIdx.x; int lane = t & 63, w = t >> 6, lq = lane >> 4, lr = lane & 15;
  int h = blockIdx.y; int c0 = blockIdx.x * 1024;
  const u16* kbase = qkv + (size_t)(512 + h * 64) * HW + c0;
  const u16* vbase = qkv + (size_t)(1024 + h * 64) * HW + c0;
  f32x4 acc[4] = {};
  for (int kt = 0; kt < 16; kt++) {
    #pragma unroll
    for (int i = 0; i < 2; i++) {
      int s = i * 256 + t; int row = s >> 3, sl = (s & 7) ^ (row & 7);
      gload16(kbase + (size_t)row * HW + kt * 64 + sl * 8, &Ws[(i * 256 + (w << 6)) * 8]);
      gload16(vbase + (size_t)row * HW + kt * 64 + sl * 8, &Vs[(i * 256 + (w << 6)) * 8]);
    }
    __syncthreads();
    #pragma unroll
    for (int kk = 0; kk < 2; kk++) {
      int rowa = w * 16 + lr;
      int sla = ((kk << 2) + lq) ^ (rowa & 7);
      bf16x8 af = *(const bf16x8*)&Ws[rowa * 64 + sla * 8];
      #pragma unroll
      for (int nj = 0; nj < 4; nj++) {
        int rowb = nj * 16 + lr;
        int slb = ((kk << 2) + lq) ^ (rowb & 7);
        bf16x8 bv = *(const bf16x8*)&Vs[rowb * 64 + slb * 8];
        acc[nj] = __builtin_amdgcn_mfma_f32_16x16x32_bf16(af, bv, acc[nj], 0, 0, 0);
      }
    }
    __syncthreads();
  }
  #pragma unroll
  for (int nj = 0; nj < 4; nj++)
    #pragma unroll
    for (int r = 0; r < 4; r++) {
      int d = w * 16 + lq * 4 + r, e = nj * 16 + lr;
      atomicAdd(&ctx[(size_t)h * 4096 + d * 64 + e], acc[nj][r]);
    }
}

// ---------------- attention out: out_t[p][h*64+e] -----------------------
__global__ __launch_bounds__(256) void k_attout(const u16* __restrict__ qkv, const float* __restrict__ ctx,
                                                const float* __restrict__ den, u16* __restrict__ outt) {
  __shared__ u16 ctxT[64 * 72];
  __shared__ u16 qs[256 * 72];
  int t = threadIdx.x; int lane = t & 63, w = t >> 6, lq = lane >> 4, lr = lane & 15;
  int h = blockIdx.y, p0 = blockIdx.x * 256;
  #pragma unroll
  for (int i = 0; i < 16; i++) {
    int idx = i * 256 + t; int d = idx >> 6, e = idx & 63;
    float v = ctx[(size_t)h * 4096 + idx] * (0.125f / den[h * 64 + d]);
    ctxT[e * 72 + d] = f2bf(v);
  }
  const u16* qbase = qkv + (size_t)(h * 64) * HW + p0;
  #pragma unroll
  for (int i = 0; i < 8; i++) {
    int idx = i * 256 + t; int d = idx >> 5, sp = idx & 31;
    uint4 v = *(const uint4*)(qbase + (size_t)d * HW + sp * 8);
    int p = sp * 8;
    qs[(p + 0) * 72 + d] = (u16)(v.x & 0xffff); qs[(p + 1) * 72 + d] = (u16)(v.x >> 16);
    qs[(p + 2) * 72 + d] = (u16)(v.y & 0xffff); qs[(p + 3) * 72 + d] = (u16)(v.y >> 16);
    qs[(p + 4) * 72 + d] = (u16)(v.z & 0xffff); qs[(p + 5) * 72 + d] = (u16)(v.z >> 16);
    qs[(p + 6) * 72 + d] = (u16)(v.w & 0xffff); qs[(p + 7) * 72 + d] = (u16)(v.w >> 16);
  }
  __syncthreads();
  f32x4 acc[4][4] = {};
  #pragma unroll
  for (int kk = 0; kk < 2; kk++) {
    bf16x8 af[4], bq[4];
    #pragma unroll
    for (int mi = 0; mi < 4; mi++)
      af[mi] = *(const bf16x8*)&ctxT[(mi * 16 + lr) * 72 + kk * 32 + lq * 8];
    #pragma unroll
    for (int nj = 0; nj < 4; nj++)
      bq[nj] = *(const bf16x8*)&qs[(w * 64 + nj * 16 + lr) * 72 + kk * 32 + lq * 8];
    #pragma unroll
    for (int mi = 0; mi < 4; mi++)
      #pragma unroll
      for (int nj = 0; nj < 4; nj++)
        acc[mi][nj] = __builtin_amdgcn_mfma_f32_16x16x32_bf16(af[mi], bq[nj], acc[mi][nj], 0, 0, 0);
  }
  #pragma unroll
  for (int mi = 0; mi < 4; mi++)
    #pragma unroll
    for (int nj = 0; nj < 4; nj++) {
      int p = p0 + w * 64 + nj * 16 + lr;
      int e0 = mi * 16 + lq * 4;
      ushort4 o;
      o.x = f2bf(acc[mi][nj][0]); o.y = f2bf(acc[mi][nj][1]);
      o.z = f2bf(acc[mi][nj][2]); o.w = f2bf(acc[mi][nj][3]);
      *(ushort4*)&outt[(size_t)p * CDIM + h * 64 + e0] = o;
    }
}

// ---------------- GEMM2: d_out = rms2(conv_w @ out_t + b), fused --------
__global__ __launch_bounds__(512) void k_gemm2(const u16* __restrict__ A, const u16* __restrict__ Bt,
                                               const float* __restrict__ bias, const float* __restrict__ g2,
                                               float* __restrict__ out) {
  __shared__ u16 As[512 * 64];   // 64 KiB
  __shared__ u16 Bs[32 * 64];    // 4 KiB
  __shared__ float css[32];
  int t = threadIdx.x; int lane = t & 63, w = t >> 6, lq = lane >> 4, lr = lane & 15;
  int bn = blockIdx.x;           // 512 blocks x 32 pixels
  if (t < 32) css[t] = 0.f;
  const u16* Bbase = Bt + (size_t)bn * 32 * CDIM;
  f32x4 acc[4][2] = {};
  for (int kt = 0; kt < 8; kt++) {
    #pragma unroll
    for (int i = 0; i < 8; i++) {
      int s = i * 512 + t;
      int row = s >> 3, slot = (s & 7) ^ (row & 7);
      gload16(A + (size_t)row * CDIM + kt * 64 + slot * 8, &As[(i * 512 + (w << 6)) * 8]);
    }
    if (w < 4) {
      int s = t;
      int row = s >> 3, slot = (s & 7) ^ (row & 7);
      gload16(Bbase + (size_t)row * CDIM + kt * 64 + slot * 8, &Bs[(w << 6) * 8]);
    }
    __syncthreads();
    #pragma unroll
    for (int kk = 0; kk < 2; kk++) {
      bf16x8 af[4], bv[2];
      #pragma unroll
      for (int mi = 0; mi < 4; mi++) {
        int row = w * 64 + mi * 16 + lr;
        int slot = ((kk << 2) + lq) ^ (row & 7);
        af[mi] = *(const bf16x8*)&As[row * 64 + slot * 8];
      }
      #pragma unroll
      for (int nj = 0; nj < 2; nj++) {
        int row = nj * 16 + lr;
        int slot = ((kk << 2) + lq) ^ (row & 7);
        bv[nj] = *(const bf16x8*)&Bs[row * 64 + slot * 8];
      }
      #pragma unroll
      for (int mi = 0; mi < 4; mi++)
        #pragma unroll
        for (int nj = 0; nj < 2; nj++)
          acc[mi][nj] = __builtin_amdgcn_mfma_f32_16x16x32_bf16(af[mi], bv[nj], acc[mi][nj], 0, 0, 0);
    }
    __syncthreads();
  }
  // epilogue: add bias, column sum-of-squares across all 512 rows, scale, store
  float bb[4][4];
  float ps[2] = {0.f, 0.f};
  #pragma unroll
  for (int mi = 0; mi < 4; mi++)
    #pragma unroll
    for (int r = 0; r < 4; r++) {
      int rowg = w * 64 + mi * 16 + lq * 4 + r;
      bb[mi][r] = bias[rowg];
      #pragma unroll
      for (int nj = 0; nj < 2; nj++) {
        float v = acc[mi][nj][r] + bb[mi][r];
        ps[nj] += v * v;
      }
    }
  #pragma unroll
  for (int nj = 0; nj < 2; nj++) {
    ps[nj] += __shfl_xor(ps[nj], 16);
    ps[nj] += __shfl_xor(ps[nj], 32);
  }
  if (lq == 0) {
    atomicAdd(&css[lr], ps[0]);
    atomicAdd(&css[16 + lr], ps[1]);
  }
  __syncthreads();
  float sc[2];
  sc[0] = SQRTD * rsqrtf(css[lr]);
  sc[1] = SQRTD * rsqrtf(css[16 + lr]);
  #pragma unroll
  for (int mi = 0; mi < 4; mi++)
    #pragma unroll
    for (int r = 0; r < 4; r++) {
      int rowg = w * 64 + mi * 16 + lq * 4 + r;
      float g = (1.0f + g2[rowg]) ;
      #pragma unroll
      for (int nj = 0; nj < 2; nj++) {
        float v = acc[mi][nj][r] + bb[mi][r];
        out[(size_t)rowg * HW + bn * 32 + nj * 16 + lr] = v * sc[nj] * g;
      }
    }
}

extern "C" void kernel_launch(void* const* d_in, const int* in_sizes, int n_in,
                              void* d_out, int out_size, void* d_ws, size_t ws_size,
                              hipStream_t stream) {
  (void)in_sizes; (void)n_in; (void)out_size; (void)ws_size;
  const float* x     = (const float*)d_in[0];
  const float* g1    = (const float*)d_in[1];
  const float* qkvw  = (const float*)d_in[2];
  const float* memkv = (const float*)d_in[3];
  const float* convw = (const float*)d_in[4];
  const float* convb = (const float*)d_in[5];
  const float* g2    = (const float*)d_in[6];
  float* out = (float*)d_out;
  char* ws = (char*)d_ws;

  float* den = (float*)(ws);                 // 2048 B
  float* ctx = (float*)(ws + 4096);          // 131072 B
  float* pss = (float*)(ws + 135168);        // 524288 B (8 x 16384 f32)
  u16* wbf   = (u16*)(ws + 659456);          // 1572864 B
  u16* cbf   = (u16*)(ws + 2232320);         // 524288 B
  u16* xnt   = (u16*)(ws + 2756608);         // 16777216 B (alias outt)
  u16* outt  = xnt;                          // xnt dead after GEMM1
  u16* qkv   = (u16*)(ws + 19533824);        // 50331648 B -> ~69.9 MB total

  k_ctxinit<<<8, 256, 0, stream>>>(memkv, den, ctx);
  k_f2bf<<<768, 256, 0, stream>>>(qkvw, wbf, 1536 * 512);
  k_f2bf<<<256, 256, 0, stream>>>(convw, cbf, 512 * 512);
  k_sumsq<<<dim3(32, 8), 256, 0, stream>>>(x, pss);
  k_xnt<<<dim3(256, 8), 256, 0, stream>>>(x, pss, g1, xnt);
  k_gemm1<<<1536, 256, 0, stream>>>(wbf, xnt, qkv, den);
  k_ctx<<<dim3(16, 8), 256, 0, stream>>>(qkv, ctx);
  k_attout<<<dim3(64, 8), 256, 0, stream>>>(qkv, ctx, den, outt);
  k_gemm2<<<512, 512, 0, stream>>>(cbf, outt, convb, g2, out);
}

// Round 3
// 105.611 us; speedup vs baseline: 1.3793x; 1.2266x over previous
//
#include <hip/hip_runtime.h>
#include <hip/hip_bf16.h>
#include <cstdint>

// LinearAttention on MI355X.
//  k_ctxinit : den = sum_j exp(mk);  ctx = mem-kv contribution
//  k_f2bf    : qkv_w fp32 -> bf16
//  k_xnt2    : one-pass rms1: x -> xn^T bf16 (sumsq + scale + transpose fused)
//  k_gemm1   : qkv = qkv_w @ xn (dbuf LDS, setprio); epilogues:
//              q -> softmax_d(q) written TRANSPOSED qT[n][hd],
//              k -> exp(k) + den atomics, v raw
//  k_ctx     : ctx += exp(k) @ v^T
//  k_fold    : M[o][hd] = sum_e convw[o][he] * ctx[h][d][e] * 0.125/den[hd]
//  k_gemm2   : d_out = rms2( M @ q' + b )  (BM=512 in-block, fused rms2)

typedef unsigned short u16;
typedef unsigned int   u32;
typedef short bf16x8 __attribute__((ext_vector_type(8)));
typedef float f32x4  __attribute__((ext_vector_type(4)));

#define HW    16384
#define CDIM  512
#define SQRTD 22.627416997969522f

__device__ __forceinline__ float bflo2f(u32 u) { union {u32 u_; float f;} c; c.u_ = u << 16;        return c.f; }
__device__ __forceinline__ float bfhi2f(u32 u) { union {u32 u_; float f;} c; c.u_ = u & 0xffff0000u; return c.f; }
__device__ __forceinline__ u16 f2bf(float f) {
  u32 x = __builtin_bit_cast(u32, f);
  u32 r = x + 0x7fffu + ((x >> 16) & 1u);
  return (u16)(r >> 16);
}

__device__ __forceinline__ void gload16(const void* g, void* l) {
  __builtin_amdgcn_global_load_lds(
      (const __attribute__((address_space(1))) void*)(uintptr_t)g,
      (__attribute__((address_space(3))) void*)(u32)(uintptr_t)l,
      16, 0, 0);
}

// ---------------- den/ctx init with mem_kv contribution -----------------
__global__ __launch_bounds__(256) void k_ctxinit(const float* __restrict__ memkv,
                                                 float* __restrict__ den, float* __restrict__ ctx) {
  int h = blockIdx.x;
  int t = threadIdx.x;
  if (t < 64) {
    const float* mk = memkv + ((size_t)h * 64 + t) * 4;
    den[h * 64 + t] = __expf(mk[0]) + __expf(mk[1]) + __expf(mk[2]) + __expf(mk[3]);
  }
  #pragma unroll
  for (int i = 0; i < 16; i++) {
    int idx = i * 256 + t; int d = idx >> 6, e = idx & 63;
    const float* mk = memkv + ((size_t)h * 64 + d) * 4;
    const float* mv = memkv + (size_t)(512 + h * 64 + e) * 4;
    ctx[(size_t)h * 4096 + idx] = __expf(mk[0]) * mv[0] + __expf(mk[1]) * mv[1]
                                + __expf(mk[2]) * mv[2] + __expf(mk[3]) * mv[3];
  }
}

__global__ __launch_bounds__(256) void k_f2bf(const float* __restrict__ src, u16* __restrict__ dst, int n) {
  int idx = (blockIdx.x * 256 + threadIdx.x) * 4;
  if (idx >= n) return;
  float4 v = *(const float4*)(src + idx);
  ushort4 o; o.x = f2bf(v.x); o.y = f2bf(v.y); o.z = f2bf(v.z); o.w = f2bf(v.w);
  *(ushort4*)(dst + idx) = o;
}

// ---------------- one-pass rms1: x -> xnt (read x once) -----------------
__global__ __launch_bounds__(512) void k_xnt2(const float* __restrict__ x, const float* __restrict__ g1,
                                              u16* __restrict__ xnt) {
  __shared__ float tl[512 * 68];   // 139264 B, pad 68 keeps float4 align + bank spread
  __shared__ float ssp[8][64];
  __shared__ float rs[64];
  __shared__ float gl[512];
  int t = threadIdx.x, l = t & 63, w = t >> 6;
  int p0 = blockIdx.x * 64;
  // load 512c x 64p as float4
  #pragma unroll
  for (int i = 0; i < 16; i++) {
    int idx = i * 512 + t;
    int c = idx >> 4, p4 = (idx & 15) * 4;
    float4 v = *(const float4*)(x + (size_t)c * HW + p0 + p4);
    *(float4*)&tl[c * 68 + p4] = v;
  }
  if (t < 512) gl[t] = 1.0f + g1[t];
  __syncthreads();
  // per-pixel partial sumsq: wave w handles channels [w*64, w*64+64)
  {
    float s = 0.f;
    #pragma unroll
    for (int c = 0; c < 64; c++) {
      float v = tl[(w * 64 + c) * 68 + l];
      s += v * v;
    }
    ssp[w][l] = s;
  }
  __syncthreads();
  if (t < 64) {
    float s = 0.f;
    #pragma unroll
    for (int j = 0; j < 8; j++) s += ssp[j][t];
    rs[t] = SQRTD * rsqrtf(s);
  }
  __syncthreads();
  // write xnt[p][c]: lane owns pixel p=l, c-chunk per (i,w)
  #pragma unroll
  for (int i = 0; i < 8; i++) {
    int c0 = (i * 8 + w) * 8;
    float sp = rs[l];
    u32 pk[4];
    #pragma unroll
    for (int j = 0; j < 4; j++) {
      float a = tl[(c0 + 2 * j) * 68 + l] * sp * gl[c0 + 2 * j];
      float b = tl[(c0 + 2 * j + 1) * 68 + l] * sp * gl[c0 + 2 * j + 1];
      pk[j] = (u32)f2bf(a) | ((u32)f2bf(b) << 16);
    }
    *(uint4*)&xnt[(size_t)(p0 + l) * CDIM + c0] = make_uint4(pk[0], pk[1], pk[2], pk[3]);
  }
}

// ---------------- GEMM1: qkv = qkv_w @ xn, dbuf + fused epilogues -------
__global__ __launch_bounds__(256) void k_gemm1(const u16* __restrict__ A, const u16* __restrict__ Bt,
                                               u16* __restrict__ Cb, u16* __restrict__ qT,
                                               float* __restrict__ den) {
  const int K = CDIM, N = HW;
  __shared__ u16 As[2][128 * 64], Bs[2][128 * 64];   // 64 KiB total
  int t = threadIdx.x;
  int lane = t & 63, w = t >> 6;
  int lq = lane >> 4, lr = lane & 15;
  // XCD-chunked swizzle: 1536 blocks, 192/XCD, bm fastest
  int wg = blockIdx.x;
  int gt = (wg & 7) * 192 + (wg >> 3);
  int bn = gt / 12, bm = gt % 12;
  int wm = (w >> 1) * 64, wn = (w & 1) * 64;
  f32x4 acc[4][4] = {};
  const u16* Abase = A + (size_t)bm * 128 * K;
  const u16* Bbase = Bt + (size_t)bn * 128 * K;

  auto STAGE = [&](int b, int kt) {
    #pragma unroll
    for (int i = 0; i < 4; i++) {
      int s = i * 256 + t;
      int row = s >> 3, slot = (s & 7) ^ (row & 7);
      gload16(Abase + (size_t)row * K + kt * 64 + slot * 8, &As[b][(i * 256 + (w << 6)) * 8]);
    }
    #pragma unroll
    for (int i = 0; i < 4; i++) {
      int s = i * 256 + t;
      int row = s >> 3, slot = (s & 7) ^ (row & 7);
      gload16(Bbase + (size_t)row * K + kt * 64 + slot * 8, &Bs[b][(i * 256 + (w << 6)) * 8]);
    }
  };

  STAGE(0, 0);
  __syncthreads();               // drains vmcnt(0) + barrier
  int cur = 0;
  for (int kt = 0; kt < 8; kt++) {
    if (kt < 7) STAGE(cur ^ 1, kt + 1);   // loads in flight across compute
    #pragma unroll
    for (int kk = 0; kk < 2; kk++) {
      bf16x8 af[4], bv[4];
      #pragma unroll
      for (int mi = 0; mi < 4; mi++) {
        int row = wm + mi * 16 + lr;
        int slot = ((kk << 2) + lq) ^ (row & 7);
        af[mi] = *(const bf16x8*)&As[cur][row * 64 + slot * 8];
      }
      #pragma unroll
      for (int nj = 0; nj < 4; nj++) {
        int row = wn + nj * 16 + lr;
        int slot = ((kk << 2) + lq) ^ (row & 7);
        bv[nj] = *(const bf16x8*)&Bs[cur][row * 64 + slot * 8];
      }
      __builtin_amdgcn_s_setprio(1);
      #pragma unroll
      for (int mi = 0; mi < 4; mi++)
        #pragma unroll
        for (int nj = 0; nj < 4; nj++)
          acc[mi][nj] = __builtin_amdgcn_mfma_f32_16x16x32_bf16(af[mi], bv[nj], acc[mi][nj], 0, 0, 0);
      __builtin_amdgcn_s_setprio(0);
    }
    __syncthreads();
    cur ^= 1;
  }
  int cm0 = bm * 128 + wm, cn0 = bn * 128 + wn;
  if (bm < 4) {
    // q rows: softmax over d (head = 64 rows, within wave rows + lq groups), store TRANSPOSED
    #pragma unroll
    for (int nj = 0; nj < 4; nj++) {
      float e[4][4];
      float s = 0.f;
      #pragma unroll
      for (int mi = 0; mi < 4; mi++)
        #pragma unroll
        for (int r = 0; r < 4; r++) { e[mi][r] = __expf(acc[mi][nj][r]); s += e[mi][r]; }
      s += __shfl_xor(s, 16);
      s += __shfl_xor(s, 32);
      float inv = 1.0f / s;
      int col = cn0 + nj * 16 + lr;     // pixel
      #pragma unroll
      for (int mi = 0; mi < 4; mi++) {
        ushort4 o;
        o.x = f2bf(e[mi][0] * inv); o.y = f2bf(e[mi][1] * inv);
        o.z = f2bf(e[mi][2] * inv); o.w = f2bf(e[mi][3] * inv);
        *(ushort4*)&qT[(size_t)col * CDIM + cm0 + mi * 16 + lq * 4] = o;
      }
    }
  } else if (bm < 8) {
    // k rows: store exp(k); accumulate row denominators
    #pragma unroll
    for (int mi = 0; mi < 4; mi++)
      #pragma unroll
      for (int r = 0; r < 4; r++) {
        int rowg = cm0 + mi * 16 + lq * 4 + r;
        float rsum = 0.f;
        #pragma unroll
        for (int nj = 0; nj < 4; nj++) {
          float e = __expf(acc[mi][nj][r]);
          rsum += e;
          Cb[(size_t)rowg * N + cn0 + nj * 16 + lr] = f2bf(e);
        }
        rsum += __shfl_xor(rsum, 1); rsum += __shfl_xor(rsum, 2);
        rsum += __shfl_xor(rsum, 4); rsum += __shfl_xor(rsum, 8);
        if (lr == 0) atomicAdd(&den[rowg - 512], rsum);
      }
  } else {
    // v rows: raw bf16
    #pragma unroll
    for (int mi = 0; mi < 4; mi++)
      #pragma unroll
      for (int nj = 0; nj < 4; nj++) {
        int col = cn0 + nj * 16 + lr;
        #pragma unroll
        for (int r = 0; r < 4; r++) {
          int rowg = cm0 + mi * 16 + lq * 4 + r;
          Cb[(size_t)rowg * N + col] = f2bf(acc[mi][nj][r]);
        }
      }
  }
}

// ---------------- ctx += exp(k) @ v^T -----------------------------------
__global__ __launch_bounds__(256) void k_ctx(const u16* __restrict__ qkv, float* __restrict__ ctx) {
  __shared__ u16 Ws[64 * 64], Vs[64 * 64];
  int t = threadIdx.x; int lane = t & 63, w = t >> 6, lq = lane >> 4, lr = lane & 15;
  int h = blockIdx.y; int c0 = blockIdx.x * 1024;
  const u16* kbase = qkv + (size_t)(512 + h * 64) * HW + c0;
  const u16* vbase = qkv + (size_t)(1024 + h * 64) * HW + c0;
  f32x4 acc[4] = {};
  for (int kt = 0; kt < 16; kt++) {
    #pragma unroll
    for (int i = 0; i < 2; i++) {
      int s = i * 256 + t; int row = s >> 3, sl = (s & 7) ^ (row & 7);
      gload16(kbase + (size_t)row * HW + kt * 64 + sl * 8, &Ws[(i * 256 + (w << 6)) * 8]);
      gload16(vbase + (size_t)row * HW + kt * 64 + sl * 8, &Vs[(i * 256 + (w << 6)) * 8]);
    }
    __syncthreads();
    #pragma unroll
    for (int kk = 0; kk < 2; kk++) {
      int rowa = w * 16 + lr;
      int sla = ((kk << 2) + lq) ^ (rowa & 7);
      bf16x8 af = *(const bf16x8*)&Ws[rowa * 64 + sla * 8];
      #pragma unroll
      for (int nj = 0; nj < 4; nj++) {
        int rowb = nj * 16 + lr;
        int slb = ((kk << 2) + lq) ^ (rowb & 7);
        bf16x8 bv = *(const bf16x8*)&Vs[rowb * 64 + slb * 8];
        acc[nj] = __builtin_amdgcn_mfma_f32_16x16x32_bf16(af, bv, acc[nj], 0, 0, 0);
      }
    }
    __syncthreads();
  }
  #pragma unroll
  for (int nj = 0; nj < 4; nj++)
    #pragma unroll
    for (int r = 0; r < 4; r++) {
      int d = w * 16 + lq * 4 + r, e = nj * 16 + lr;
      atomicAdd(&ctx[(size_t)h * 4096 + d * 64 + e], acc[nj][r]);
    }
}

// ---------------- fold conv_w into ctx: M[o][hd] ------------------------
__global__ __launch_bounds__(256) void k_fold(const float* __restrict__ convw, const float* __restrict__ ctx,
                                              const float* __restrict__ den, u16* __restrict__ Mbf) {
  __shared__ float cn[64 * 65];
  __shared__ float dn[64];
  int t = threadIdx.x;
  int h = blockIdx.x & 7, oc = blockIdx.x >> 3;
  if (t < 64) dn[t] = 0.125f / den[h * 64 + t];
  __syncthreads();
  #pragma unroll
  for (int i = 0; i < 16; i++) {
    int idx = i * 256 + t;             // d*64 + e
    int d = idx >> 6, e = idx & 63;
    cn[d * 65 + e] = ctx[(size_t)h * 4096 + idx] * dn[d];
  }
  __syncthreads();
  int o = oc * 64 + (t >> 2);
  int d0 = (t & 3) * 16;
  float Wr[64];
  const float* wp = convw + (size_t)o * CDIM + h * 64;
  #pragma unroll
  for (int e4 = 0; e4 < 16; e4++) {
    float4 v = *(const float4*)(wp + e4 * 4);
    Wr[e4 * 4] = v.x; Wr[e4 * 4 + 1] = v.y; Wr[e4 * 4 + 2] = v.z; Wr[e4 * 4 + 3] = v.w;
  }
  float outv[16];
  #pragma unroll
  for (int dd = 0; dd < 16; dd++) {
    float a = 0.f;
    #pragma unroll
    for (int e = 0; e < 64; e++) a += Wr[e] * cn[(d0 + dd) * 65 + e];
    outv[dd] = a;
  }
  u32 pk[4];
  #pragma unroll
  for (int j = 0; j < 8; j++)
    pk[j >> 1] = (j & 1) ? (pk[j >> 1] | ((u32)f2bf(outv[j * 2 + 1]) << 16))
                         : (u32)f2bf(outv[j * 2]);
  // rebuild cleanly (avoid read-before-write of pk):
  #pragma unroll
  for (int j = 0; j < 4; j++)
    pk[j] = (u32)f2bf(outv[j * 4]) | ((u32)f2bf(outv[j * 4 + 1]) << 16);
  u32 pk2[2];
  (void)pk2;
  // store 16 u16 = 2 x uint2-of-bf16 pairs -> use 4 u32 stores
  #pragma unroll
  for (int j = 0; j < 8; j++) {
    u32 v = (u32)f2bf(outv[j * 2]) | ((u32)f2bf(outv[j * 2 + 1]) << 16);
    *(u32*)&Mbf[(size_t)o * CDIM + h * 64 + d0 + j * 2] = v;
  }
}

// ---------------- GEMM2: d_out = rms2(M @ q' + b), fused ----------------
__global__ __launch_bounds__(512) void k_gemm2(const u16* __restrict__ A, const u16* __restrict__ Bt,
                                               const float* __restrict__ bias, const float* __restrict__ g2,
                                               float* __restrict__ out) {
  __shared__ u16 As[512 * 64];   // 64 KiB
  __shared__ u16 Bs[32 * 64];    // 4 KiB
  __shared__ float css[32];
  int t = threadIdx.x; int lane = t & 63, w = t >> 6, lq = lane >> 4, lr = lane & 15;
  int bn = blockIdx.x;           // 512 blocks x 32 pixels
  if (t < 32) css[t] = 0.f;
  const u16* Bbase = Bt + (size_t)bn * 32 * CDIM;
  f32x4 acc[4][2] = {};
  for (int kt = 0; kt < 8; kt++) {
    #pragma unroll
    for (int i = 0; i < 8; i++) {
      int s = i * 512 + t;
      int row = s >> 3, slot = (s & 7) ^ (row & 7);
      gload16(A + (size_t)row * CDIM + kt * 64 + slot * 8, &As[(i * 512 + (w << 6)) * 8]);
    }
    if (w < 4) {
      int s = t;
      int row = s >> 3, slot = (s & 7) ^ (row & 7);
      gload16(Bbase + (size_t)row * CDIM + kt * 64 + slot * 8, &Bs[(w << 6) * 8]);
    }
    __syncthreads();
    #pragma unroll
    for (int kk = 0; kk < 2; kk++) {
      bf16x8 af[4], bv[2];
      #pragma unroll
      for (int mi = 0; mi < 4; mi++) {
        int row = w * 64 + mi * 16 + lr;
        int slot = ((kk << 2) + lq) ^ (row & 7);
        af[mi] = *(const bf16x8*)&As[row * 64 + slot * 8];
      }
      #pragma unroll
      for (int nj = 0; nj < 2; nj++) {
        int row = nj * 16 + lr;
        int slot = ((kk << 2) + lq) ^ (row & 7);
        bv[nj] = *(const bf16x8*)&Bs[row * 64 + slot * 8];
      }
      __builtin_amdgcn_s_setprio(1);
      #pragma unroll
      for (int mi = 0; mi < 4; mi++)
        #pragma unroll
        for (int nj = 0; nj < 2; nj++)
          acc[mi][nj] = __builtin_amdgcn_mfma_f32_16x16x32_bf16(af[mi], bv[nj], acc[mi][nj], 0, 0, 0);
      __builtin_amdgcn_s_setprio(0);
    }
    __syncthreads();
  }
  float bb[4][4];
  float ps[2] = {0.f, 0.f};
  #pragma unroll
  for (int mi = 0; mi < 4; mi++)
    #pragma unroll
    for (int r = 0; r < 4; r++) {
      int rowg = w * 64 + mi * 16 + lq * 4 + r;
      bb[mi][r] = bias[rowg];
      #pragma unroll
      for (int nj = 0; nj < 2; nj++) {
        float v = acc[mi][nj][r] + bb[mi][r];
        ps[nj] += v * v;
      }
    }
  #pragma unroll
  for (int nj = 0; nj < 2; nj++) {
    ps[nj] += __shfl_xor(ps[nj], 16);
    ps[nj] += __shfl_xor(ps[nj], 32);
  }
  if (lq == 0) {
    atomicAdd(&css[lr], ps[0]);
    atomicAdd(&css[16 + lr], ps[1]);
  }
  __syncthreads();
  float sc[2];
  sc[0] = SQRTD * rsqrtf(css[lr]);
  sc[1] = SQRTD * rsqrtf(css[16 + lr]);
  #pragma unroll
  for (int mi = 0; mi < 4; mi++)
    #pragma unroll
    for (int r = 0; r < 4; r++) {
      int rowg = w * 64 + mi * 16 + lq * 4 + r;
      float g = 1.0f + g2[rowg];
      #pragma unroll
      for (int nj = 0; nj < 2; nj++) {
        float v = acc[mi][nj][r] + bb[mi][r];
        out[(size_t)rowg * HW + bn * 32 + nj * 16 + lr] = v * sc[nj] * g;
      }
    }
}

extern "C" void kernel_launch(void* const* d_in, const int* in_sizes, int n_in,
                              void* d_out, int out_size, void* d_ws, size_t ws_size,
                              hipStream_t stream) {
  (void)in_sizes; (void)n_in; (void)out_size; (void)ws_size;
  const float* x     = (const float*)d_in[0];
  const float* g1    = (const float*)d_in[1];
  const float* qkvw  = (const float*)d_in[2];
  const float* memkv = (const float*)d_in[3];
  const float* convw = (const float*)d_in[4];
  const float* convb = (const float*)d_in[5];
  const float* g2    = (const float*)d_in[6];
  float* out = (float*)d_out;
  char* ws = (char*)d_ws;

  float* den = (float*)(ws);                 // 2048 B
  float* ctx = (float*)(ws + 4096);          // 131072 B
  u16* Mbf   = (u16*)(ws + 139264);          // 524288 B
  u16* wbf   = (u16*)(ws + 663552);          // 1572864 B
  u16* xnt   = (u16*)(ws + 2236416);         // 16777216 B
  u16* qkv   = (u16*)(ws + 19013632);        // 50331648 B -> ~69.3 MB total
  u16* qT    = qkv;                          // q-slice reused as qT[16384][512]

  k_ctxinit<<<8, 256, 0, stream>>>(memkv, den, ctx);
  k_f2bf<<<768, 256, 0, stream>>>(qkvw, wbf, 1536 * 512);
  k_xnt2<<<256, 512, 0, stream>>>(x, g1, xnt);
  k_gemm1<<<1536, 256, 0, stream>>>(wbf, xnt, qkv, qT, den);
  k_ctx<<<dim3(16, 8), 256, 0, stream>>>(qkv, ctx);
  k_fold<<<64, 256, 0, stream>>>(convw, ctx, den, Mbf);
  k_gemm2<<<512, 512, 0, stream>>>(Mbf, qT, convb, g2, out);
}

// Round 4
// 102.435 us; speedup vs baseline: 1.4221x; 1.0310x over previous
//
#include <hip/hip_runtime.h>
#include <hip/hip_bf16.h>
#include <cstdint>

// LinearAttention on MI355X.
//  k_pre   : (merged) rms1 one-pass x->xn^T bf16  +  qkv_w f2bf slice  +  ctx/den init
//  k_gemm1 : qkv = qkv_w @ xn — counted-vmcnt(8) 2-ahead pipeline, raw barriers,
//            setprio MFMA clusters; fused epilogues (q-softmax->qT, exp(k)+den, v raw)
//  k_ctx   : ctx += exp(k) @ v^T  (256 blocks)
//  k_fold  : M[o][hd] = sum_e convw[o][he] * ctx[h][d][e] * 0.125/den[hd]
//  k_gemm2 : d_out = rms2( M @ q' + b )  (BM=512 in-block, fused rms2)

typedef unsigned short u16;
typedef unsigned int   u32;
typedef short bf16x8 __attribute__((ext_vector_type(8)));
typedef float f32x4  __attribute__((ext_vector_type(4)));

#define HW    16384
#define CDIM  512
#define SQRTD 22.627416997969522f

#define WAITV8 asm volatile("s_waitcnt vmcnt(8)" ::: "memory")
#define WAITV0 asm volatile("s_waitcnt vmcnt(0)" ::: "memory")
#define WAITL0 asm volatile("s_waitcnt lgkmcnt(0)" ::: "memory")

__device__ __forceinline__ float bflo2f(u32 u) { union {u32 u_; float f;} c; c.u_ = u << 16;        return c.f; }
__device__ __forceinline__ float bfhi2f(u32 u) { union {u32 u_; float f;} c; c.u_ = u & 0xffff0000u; return c.f; }
__device__ __forceinline__ u16 f2bf(float f) {
  u32 x = __builtin_bit_cast(u32, f);
  u32 r = x + 0x7fffu + ((x >> 16) & 1u);
  return (u16)(r >> 16);
}

__device__ __forceinline__ void gload16(const void* g, void* l) {
  __builtin_amdgcn_global_load_lds(
      (const __attribute__((address_space(1))) void*)(uintptr_t)g,
      (__attribute__((address_space(3))) void*)(u32)(uintptr_t)l,
      16, 0, 0);
}

// ---------------- merged prologue: xnt + f2bf(qkvw) + ctx/den init ------
__global__ __launch_bounds__(512) void k_pre(const float* __restrict__ x, const float* __restrict__ g1,
                                             const float* __restrict__ qkvw, const float* __restrict__ memkv,
                                             u16* __restrict__ xnt, u16* __restrict__ wbf,
                                             float* __restrict__ den, float* __restrict__ ctx) {
  __shared__ float tl[512 * 68];   // 139264 B
  __shared__ float ssp[8][64];
  __shared__ float rs[64];
  __shared__ float gl[512];
  int t = threadIdx.x, l = t & 63, w = t >> 6;
  int b = blockIdx.x;
  int p0 = b * 64;
  // ---- xnt part (all 256 blocks) ----
  #pragma unroll
  for (int i = 0; i < 16; i++) {
    int idx = i * 512 + t;
    int c = idx >> 4, p4 = (idx & 15) * 4;
    float4 v = *(const float4*)(x + (size_t)c * HW + p0 + p4);
    *(float4*)&tl[c * 68 + p4] = v;
  }
  if (t < 512) gl[t] = 1.0f + g1[t];
  __syncthreads();
  {
    float s = 0.f;
    #pragma unroll
    for (int c = 0; c < 64; c++) {
      float v = tl[(w * 64 + c) * 68 + l];
      s += v * v;
    }
    ssp[w][l] = s;
  }
  __syncthreads();
  if (t < 64) {
    float s = 0.f;
    #pragma unroll
    for (int j = 0; j < 8; j++) s += ssp[j][t];
    rs[t] = SQRTD * rsqrtf(s);
  }
  __syncthreads();
  #pragma unroll
  for (int i = 0; i < 8; i++) {
    int c0 = (i * 8 + w) * 8;
    float sp = rs[l];
    u32 pk[4];
    #pragma unroll
    for (int j = 0; j < 4; j++) {
      float a = tl[(c0 + 2 * j) * 68 + l] * sp * gl[c0 + 2 * j];
      float bq = tl[(c0 + 2 * j + 1) * 68 + l] * sp * gl[c0 + 2 * j + 1];
      pk[j] = (u32)f2bf(a) | ((u32)f2bf(bq) << 16);
    }
    *(uint4*)&xnt[(size_t)(p0 + l) * CDIM + c0] = make_uint4(pk[0], pk[1], pk[2], pk[3]);
  }
  // ---- f2bf slice (grid-stride over 1536*512 floats) ----
  #pragma unroll
  for (int sweep = 0; sweep < 2; sweep++) {
    int idx = (sweep * 256 * 512 + b * 512 + t) * 4;
    if (idx < 1536 * 512) {
      float4 v = *(const float4*)(qkvw + idx);
      ushort4 o; o.x = f2bf(v.x); o.y = f2bf(v.y); o.z = f2bf(v.z); o.w = f2bf(v.w);
      *(ushort4*)(wbf + idx) = o;
    }
  }
  // ---- ctx/den init (block 0 only) ----
  if (b == 0) {
    if (t < 512) {
      int h = t >> 6, d = t & 63;
      const float* mk = memkv + ((size_t)h * 64 + d) * 4;
      den[t] = __expf(mk[0]) + __expf(mk[1]) + __expf(mk[2]) + __expf(mk[3]);
    }
    #pragma unroll
    for (int i = 0; i < 8; i++) {
      int idx = i * 512 + t;           // h*4096 span handled over 8 iters * 8 h
      int hh = idx >> 9;               // 0..7 within this iter? no: idx<4096 covers h=0 only
      (void)hh;
    }
    // full 8 heads x 4096:
    for (int i = 0; i < 64; i++) {
      int idx = i * 512 + t;           // 0..32767
      int h = idx >> 12, de = idx & 4095;
      int d = de >> 6, e = de & 63;
      const float* mk = memkv + ((size_t)h * 64 + d) * 4;
      const float* mv = memkv + (size_t)(512 + h * 64 + e) * 4;
      ctx[idx] = __expf(mk[0]) * mv[0] + __expf(mk[1]) * mv[1]
               + __expf(mk[2]) * mv[2] + __expf(mk[3]) * mv[3];
    }
  }
}

// ---------------- GEMM1: counted-vmcnt pipeline + fused epilogues -------
__global__ __launch_bounds__(256, 2) void k_gemm1(const u16* __restrict__ A, const u16* __restrict__ Bt,
                                                  u16* __restrict__ Cb, u16* __restrict__ qT,
                                                  float* __restrict__ den) {
  const int K = CDIM, N = HW;
  __shared__ u16 As[2][128 * 64], Bs[2][128 * 64];   // 64 KiB
  int t = threadIdx.x;
  int lane = t & 63, w = t >> 6;
  int lq = lane >> 4, lr = lane & 15;
  int wg = blockIdx.x;
  int gt = (wg & 7) * 192 + (wg >> 3);
  int bn = gt / 12, bm = gt % 12;
  int wm = (w >> 1) * 64, wn = (w & 1) * 64;
  f32x4 acc[4][4] = {};
  const u16* Abase = A + (size_t)bm * 128 * K;
  const u16* Bbase = Bt + (size_t)bn * 128 * K;

  auto STAGE = [&](int buf, int kt) {
    #pragma unroll
    for (int i = 0; i < 4; i++) {
      int s = i * 256 + t;
      int row = s >> 3, slot = (s & 7) ^ (row & 7);
      gload16(Abase + (size_t)row * K + kt * 64 + slot * 8, &As[buf][(i * 256 + (w << 6)) * 8]);
    }
    #pragma unroll
    for (int i = 0; i < 4; i++) {
      int s = i * 256 + t;
      int row = s >> 3, slot = (s & 7) ^ (row & 7);
      gload16(Bbase + (size_t)row * K + kt * 64 + slot * 8, &Bs[buf][(i * 256 + (w << 6)) * 8]);
    }
  };
  auto FRAGS = [&](int buf, int kk, bf16x8* af, bf16x8* bv) {
    #pragma unroll
    for (int mi = 0; mi < 4; mi++) {
      int row = wm + mi * 16 + lr;
      int slot = ((kk << 2) + lq) ^ (row & 7);
      af[mi] = *(const bf16x8*)&As[buf][row * 64 + slot * 8];
    }
    #pragma unroll
    for (int nj = 0; nj < 4; nj++) {
      int row = wn + nj * 16 + lr;
      int slot = ((kk << 2) + lq) ^ (row & 7);
      bv[nj] = *(const bf16x8*)&Bs[buf][row * 64 + slot * 8];
    }
  };

  STAGE(0, 0);
  STAGE(1, 1);
  // pipeline: at iter t, outstanding = loads(t)[8] + loads(t+1)[8]; vmcnt(8) => buf[t] done
  for (int kt = 0; kt < 7; kt++) {
    int buf = kt & 1;
    WAITV8;
    __builtin_amdgcn_s_barrier();        // buf[kt] visible from all waves
    bf16x8 af0[4], bv0[4], af1[4], bv1[4];
    FRAGS(buf, 0, af0, bv0);
    FRAGS(buf, 1, af1, bv1);
    WAITL0;                              // all my ds_reads of buf[kt] landed
    __builtin_amdgcn_s_barrier();        // all waves done reading buf[kt]
    if (kt < 6) STAGE(buf, kt + 2);      // refill; flies across MFMA + next barrier
    __builtin_amdgcn_s_setprio(1);
    #pragma unroll
    for (int mi = 0; mi < 4; mi++)
      #pragma unroll
      for (int nj = 0; nj < 4; nj++)
        acc[mi][nj] = __builtin_amdgcn_mfma_f32_16x16x32_bf16(af0[mi], bv0[nj], acc[mi][nj], 0, 0, 0);
    #pragma unroll
    for (int mi = 0; mi < 4; mi++)
      #pragma unroll
      for (int nj = 0; nj < 4; nj++)
        acc[mi][nj] = __builtin_amdgcn_mfma_f32_16x16x32_bf16(af1[mi], bv1[nj], acc[mi][nj], 0, 0, 0);
    __builtin_amdgcn_s_setprio(0);
  }
  {
    WAITV0;
    __builtin_amdgcn_s_barrier();
    bf16x8 af0[4], bv0[4], af1[4], bv1[4];
    FRAGS(1, 0, af0, bv0);
    FRAGS(1, 1, af1, bv1);
    __builtin_amdgcn_s_setprio(1);
    #pragma unroll
    for (int mi = 0; mi < 4; mi++)
      #pragma unroll
      for (int nj = 0; nj < 4; nj++)
        acc[mi][nj] = __builtin_amdgcn_mfma_f32_16x16x32_bf16(af0[mi], bv0[nj], acc[mi][nj], 0, 0, 0);
    #pragma unroll
    for (int mi = 0; mi < 4; mi++)
      #pragma unroll
      for (int nj = 0; nj < 4; nj++)
        acc[mi][nj] = __builtin_amdgcn_mfma_f32_16x16x32_bf16(af1[mi], bv1[nj], acc[mi][nj], 0, 0, 0);
    __builtin_amdgcn_s_setprio(0);
  }

  int cm0 = bm * 128 + wm, cn0 = bn * 128 + wn;
  if (bm < 4) {
    // q rows: softmax over d (64-row head per wave half) -> qT transposed
    #pragma unroll
    for (int nj = 0; nj < 4; nj++) {
      float e[4][4];
      float s = 0.f;
      #pragma unroll
      for (int mi = 0; mi < 4; mi++)
        #pragma unroll
        for (int r = 0; r < 4; r++) { e[mi][r] = __expf(acc[mi][nj][r]); s += e[mi][r]; }
      s += __shfl_xor(s, 16);
      s += __shfl_xor(s, 32);
      float inv = 1.0f / s;
      int col = cn0 + nj * 16 + lr;
      #pragma unroll
      for (int mi = 0; mi < 4; mi++) {
        ushort4 o;
        o.x = f2bf(e[mi][0] * inv); o.y = f2bf(e[mi][1] * inv);
        o.z = f2bf(e[mi][2] * inv); o.w = f2bf(e[mi][3] * inv);
        *(ushort4*)&qT[(size_t)col * CDIM + cm0 + mi * 16 + lq * 4] = o;
      }
    }
  } else if (bm < 8) {
    #pragma unroll
    for (int mi = 0; mi < 4; mi++)
      #pragma unroll
      for (int r = 0; r < 4; r++) {
        int rowg = cm0 + mi * 16 + lq * 4 + r;
        float rsum = 0.f;
        #pragma unroll
        for (int nj = 0; nj < 4; nj++) {
          float e = __expf(acc[mi][nj][r]);
          rsum += e;
          Cb[(size_t)rowg * N + cn0 + nj * 16 + lr] = f2bf(e);
        }
        rsum += __shfl_xor(rsum, 1); rsum += __shfl_xor(rsum, 2);
        rsum += __shfl_xor(rsum, 4); rsum += __shfl_xor(rsum, 8);
        if (lr == 0) atomicAdd(&den[rowg - 512], rsum);
      }
  } else {
    #pragma unroll
    for (int mi = 0; mi < 4; mi++)
      #pragma unroll
      for (int nj = 0; nj < 4; nj++) {
        int col = cn0 + nj * 16 + lr;
        #pragma unroll
        for (int r = 0; r < 4; r++) {
          int rowg = cm0 + mi * 16 + lq * 4 + r;
          Cb[(size_t)rowg * N + col] = f2bf(acc[mi][nj][r]);
        }
      }
  }
}

// ---------------- ctx += exp(k) @ v^T (256 blocks) ----------------------
__global__ __launch_bounds__(256) void k_ctx(const u16* __restrict__ qkv, float* __restrict__ ctx) {
  __shared__ u16 Ws[64 * 64], Vs[64 * 64];
  int t = threadIdx.x; int lane = t & 63, w = t >> 6, lq = lane >> 4, lr = lane & 15;
  int h = blockIdx.y; int c0 = blockIdx.x * 512;
  const u16* kbase = qkv + (size_t)(512 + h * 64) * HW + c0;
  const u16* vbase = qkv + (size_t)(1024 + h * 64) * HW + c0;
  f32x4 acc[4] = {};
  for (int kt = 0; kt < 8; kt++) {
    #pragma unroll
    for (int i = 0; i < 2; i++) {
      int s = i * 256 + t; int row = s >> 3, sl = (s & 7) ^ (row & 7);
      gload16(kbase + (size_t)row * HW + kt * 64 + sl * 8, &Ws[(i * 256 + (w << 6)) * 8]);
      gload16(vbase + (size_t)row * HW + kt * 64 + sl * 8, &Vs[(i * 256 + (w << 6)) * 8]);
    }
    __syncthreads();
    #pragma unroll
    for (int kk = 0; kk < 2; kk++) {
      int rowa = w * 16 + lr;
      int sla = ((kk << 2) + lq) ^ (rowa & 7);
      bf16x8 af = *(const bf16x8*)&Ws[rowa * 64 + sla * 8];
      #pragma unroll
      for (int nj = 0; nj < 4; nj++) {
        int rowb = nj * 16 + lr;
        int slb = ((kk << 2) + lq) ^ (rowb & 7);
        bf16x8 bv = *(const bf16x8*)&Vs[rowb * 64 + slb * 8];
        acc[nj] = __builtin_amdgcn_mfma_f32_16x16x32_bf16(af, bv, acc[nj], 0, 0, 0);
      }
    }
    __syncthreads();
  }
  #pragma unroll
  for (int nj = 0; nj < 4; nj++)
    #pragma unroll
    for (int r = 0; r < 4; r++) {
      int d = w * 16 + lq * 4 + r, e = nj * 16 + lr;
      atomicAdd(&ctx[(size_t)h * 4096 + d * 64 + e], acc[nj][r]);
    }
}

// ---------------- fold conv_w into ctx: M[o][hd] ------------------------
__global__ __launch_bounds__(256) void k_fold(const float* __restrict__ convw, const float* __restrict__ ctx,
                                              const float* __restrict__ den, u16* __restrict__ Mbf) {
  __shared__ float cn[64 * 65];
  __shared__ float dn[64];
  int t = threadIdx.x;
  int h = blockIdx.x & 7, oc = blockIdx.x >> 3;
  if (t < 64) dn[t] = 0.125f / den[h * 64 + t];
  __syncthreads();
  #pragma unroll
  for (int i = 0; i < 16; i++) {
    int idx = i * 256 + t;
    int d = idx >> 6, e = idx & 63;
    cn[d * 65 + e] = ctx[(size_t)h * 4096 + idx] * dn[d];
  }
  __syncthreads();
  int o = oc * 64 + (t >> 2);
  int d0 = (t & 3) * 16;
  float Wr[64];
  const float* wp = convw + (size_t)o * CDIM + h * 64;
  #pragma unroll
  for (int e4 = 0; e4 < 16; e4++) {
    float4 v = *(const float4*)(wp + e4 * 4);
    Wr[e4 * 4] = v.x; Wr[e4 * 4 + 1] = v.y; Wr[e4 * 4 + 2] = v.z; Wr[e4 * 4 + 3] = v.w;
  }
  float outv[16];
  #pragma unroll
  for (int dd = 0; dd < 16; dd++) {
    float a = 0.f;
    #pragma unroll
    for (int e = 0; e < 64; e++) a += Wr[e] * cn[(d0 + dd) * 65 + e];
    outv[dd] = a;
  }
  #pragma unroll
  for (int j = 0; j < 8; j++) {
    u32 v = (u32)f2bf(outv[j * 2]) | ((u32)f2bf(outv[j * 2 + 1]) << 16);
    *(u32*)&Mbf[(size_t)o * CDIM + h * 64 + d0 + j * 2] = v;
  }
}

// ---------------- GEMM2: d_out = rms2(M @ q' + b), fused ----------------
__global__ __launch_bounds__(512) void k_gemm2(const u16* __restrict__ A, const u16* __restrict__ Bt,
                                               const float* __restrict__ bias, const float* __restrict__ g2,
                                               float* __restrict__ out) {
  __shared__ u16 As[512 * 64];
  __shared__ u16 Bs[32 * 64];
  __shared__ float css[32];
  int t = threadIdx.x; int lane = t & 63, w = t >> 6, lq = lane >> 4, lr = lane & 15;
  int bn = blockIdx.x;
  if (t < 32) css[t] = 0.f;
  const u16* Bbase = Bt + (size_t)bn * 32 * CDIM;
  f32x4 acc[4][2] = {};
  for (int kt = 0; kt < 8; kt++) {
    #pragma unroll
    for (int i = 0; i < 8; i++) {
      int s = i * 512 + t;
      int row = s >> 3, slot = (s & 7) ^ (row & 7);
      gload16(A + (size_t)row * CDIM + kt * 64 + slot * 8, &As[(i * 512 + (w << 6)) * 8]);
    }
    if (w < 4) {
      int s = t;
      int row = s >> 3, slot = (s & 7) ^ (row & 7);
      gload16(Bbase + (size_t)row * CDIM + kt * 64 + slot * 8, &Bs[(w << 6) * 8]);
    }
    __syncthreads();
    #pragma unroll
    for (int kk = 0; kk < 2; kk++) {
      bf16x8 af[4], bv[2];
      #pragma unroll
      for (int mi = 0; mi < 4; mi++) {
        int row = w * 64 + mi * 16 + lr;
        int slot = ((kk << 2) + lq) ^ (row & 7);
        af[mi] = *(const bf16x8*)&As[row * 64 + slot * 8];
      }
      #pragma unroll
      for (int nj = 0; nj < 2; nj++) {
        int row = nj * 16 + lr;
        int slot = ((kk << 2) + lq) ^ (row & 7);
        bv[nj] = *(const bf16x8*)&Bs[row * 64 + slot * 8];
      }
      __builtin_amdgcn_s_setprio(1);
      #pragma unroll
      for (int mi = 0; mi < 4; mi++)
        #pragma unroll
        for (int nj = 0; nj < 2; nj++)
          acc[mi][nj] = __builtin_amdgcn_mfma_f32_16x16x32_bf16(af[mi], bv[nj], acc[mi][nj], 0, 0, 0);
      __builtin_amdgcn_s_setprio(0);
    }
    __syncthreads();
  }
  float bb[4][4];
  float ps[2] = {0.f, 0.f};
  #pragma unroll
  for (int mi = 0; mi < 4; mi++)
    #pragma unroll
    for (int r = 0; r < 4; r++) {
      int rowg = w * 64 + mi * 16 + lq * 4 + r;
      bb[mi][r] = bias[rowg];
      #pragma unroll
      for (int nj = 0; nj < 2; nj++) {
        float v = acc[mi][nj][r] + bb[mi][r];
        ps[nj] += v * v;
      }
    }
  #pragma unroll
  for (int nj = 0; nj < 2; nj++) {
    ps[nj] += __shfl_xor(ps[nj], 16);
    ps[nj] += __shfl_xor(ps[nj], 32);
  }
  if (lq == 0) {
    atomicAdd(&css[lr], ps[0]);
    atomicAdd(&css[16 + lr], ps[1]);
  }
  __syncthreads();
  float sc[2];
  sc[0] = SQRTD * rsqrtf(css[lr]);
  sc[1] = SQRTD * rsqrtf(css[16 + lr]);
  #pragma unroll
  for (int mi = 0; mi < 4; mi++)
    #pragma unroll
    for (int r = 0; r < 4; r++) {
      int rowg = w * 64 + mi * 16 + lq * 4 + r;
      float g = 1.0f + g2[rowg];
      #pragma unroll
      for (int nj = 0; nj < 2; nj++) {
        float v = acc[mi][nj][r] + bb[mi][r];
        out[(size_t)rowg * HW + bn * 32 + nj * 16 + lr] = v * sc[nj] * g;
      }
    }
}

extern "C" void kernel_launch(void* const* d_in, const int* in_sizes, int n_in,
                              void* d_out, int out_size, void* d_ws, size_t ws_size,
                              hipStream_t stream) {
  (void)in_sizes; (void)n_in; (void)out_size; (void)ws_size;
  const float* x     = (const float*)d_in[0];
  const float* g1    = (const float*)d_in[1];
  const float* qkvw  = (const float*)d_in[2];
  const float* memkv = (const float*)d_in[3];
  const float* convw = (const float*)d_in[4];
  const float* convb = (const float*)d_in[5];
  const float* g2    = (const float*)d_in[6];
  float* out = (float*)d_out;
  char* ws = (char*)d_ws;

  float* den = (float*)(ws);                 // 2048 B
  float* ctx = (float*)(ws + 4096);          // 131072 B
  u16* Mbf   = (u16*)(ws + 139264);          // 524288 B
  u16* wbf   = (u16*)(ws + 663552);          // 1572864 B
  u16* xnt   = (u16*)(ws + 2236416);         // 16777216 B
  u16* qkv   = (u16*)(ws + 19013632);        // 50331648 B -> ~69.3 MB total
  u16* qT    = qkv;                          // q-slice reused as qT[16384][512]

  k_pre<<<256, 512, 0, stream>>>(x, g1, qkvw, memkv, xnt, wbf, den, ctx);
  k_gemm1<<<1536, 256, 0, stream>>>(wbf, xnt, qkv, qT, den);
  k_ctx<<<dim3(32, 8), 256, 0, stream>>>(qkv, ctx);
  k_fold<<<64, 256, 0, stream>>>(convw, ctx, den, Mbf);
  k_gemm2<<<512, 512, 0, stream>>>(Mbf, qT, convb, g2, out);
}